// Round 4
// baseline (271.991 us; speedup 1.0000x reference)
//
#include <hip/hip_runtime.h>
#include <cstdint>

// BFP quantize: block = channel vector at each (n,h,w), NCHW layout.
// N=64, C=256, H=W=56, mantissa_bits=3.
// delta = 2^(e-3), max_abs = m*2^e, m in [0.5,1) (frexp). q = trunc(x/delta)*delta.
// Exact pow2 arithmetic — absmax==0 verified R1/R2.
//
// R3b: low-register 2-sweep variant. Pass A: running abs-max (no v[] array)
// -> 8 waves/SIMD. Butterfly shfl_xor across the 16 lanes sharing a site.
// Pass B: re-read (L3-resident, proven R1: FETCH stayed at input size)
// + quantize + NONTEMPORAL store via native ext_vector type (HIP_vector_type
// rejected by the builtin — R3 compile fail).

constexpr int C     = 256;
constexpr int HW    = 56 * 56;   // 3136
constexpr int HW4   = HW / 4;    // 784 float4 per (n,c) plane
constexpr int CHW4  = C * HW4;   // float4 per image
constexpr int CHUNK = 16;        // channels per lane (16 lanes cover C=256)

typedef float vfloat4 __attribute__((ext_vector_type(4)));  // native vec for builtins

__device__ __forceinline__ int fexp(float x) {
    int e;
    (void)frexpf(x, &e);         // v_frexp_exp_i32_f32; e=0 for x==0
    return e;
}

__device__ __forceinline__ void fmax4(float4& m, const float4& v) {
    m.x = fmaxf(m.x, fabsf(v.x));
    m.y = fmaxf(m.y, fabsf(v.y));
    m.z = fmaxf(m.z, fabsf(v.z));
    m.w = fmaxf(m.w, fabsf(v.w));
}

__global__ __launch_bounds__(256, 8)
void bfp_kernel(const float4* __restrict__ in, float4* __restrict__ out, int total4) {
    int tid  = blockIdx.x * 256 + threadIdx.x;
    int wave = tid >> 6;
    int lane = threadIdx.x & 63;
    int s    = wave * 4 + (lane & 3);     // float4 spatial-site index
    if (s >= total4) return;
    int k    = lane >> 2;                 // channel chunk 0..15

    int n  = s / HW4;
    int s4 = s - n * HW4;

    const float4* p = in  + (size_t)n * CHW4 + (size_t)k * CHUNK * HW4 + s4;
    float4*       q = out + (size_t)n * CHW4 + (size_t)k * CHUNK * HW4 + s4;

    // ---- pass A: running abs-max over 16 channels, 4 accumulators for ILP ----
    float4 m0 = make_float4(0.f, 0.f, 0.f, 0.f), m1 = m0, m2 = m0, m3 = m0;
#pragma unroll
    for (int i = 0; i < CHUNK; i += 4) {
        float4 a = p[(i + 0) * HW4];
        float4 b = p[(i + 1) * HW4];
        float4 c = p[(i + 2) * HW4];
        float4 d = p[(i + 3) * HW4];
        fmax4(m0, a); fmax4(m1, b); fmax4(m2, c); fmax4(m3, d);
    }
    float4 m;
    m.x = fmaxf(fmaxf(m0.x, m1.x), fmaxf(m2.x, m3.x));
    m.y = fmaxf(fmaxf(m0.y, m1.y), fmaxf(m2.y, m3.y));
    m.z = fmaxf(fmaxf(m0.z, m1.z), fmaxf(m2.z, m3.z));
    m.w = fmaxf(fmaxf(m0.w, m1.w), fmaxf(m2.w, m3.w));

    // ---- butterfly reduce across the 16 lanes sharing this site ----
#pragma unroll
    for (int mask = 4; mask < 64; mask <<= 1) {
        m.x = fmaxf(m.x, __shfl_xor(m.x, mask));
        m.y = fmaxf(m.y, __shfl_xor(m.y, mask));
        m.z = fmaxf(m.z, __shfl_xor(m.z, mask));
        m.w = fmaxf(m.w, __shfl_xor(m.w, mask));
    }

    // ---- shared exponent -> delta = 2^(e-3), inv = 2^(3-e) (both exact) ----
    int ex = fexp(m.x), ey = fexp(m.y), ez = fexp(m.z), ew = fexp(m.w);
    float dx = ldexpf(1.f, ex - 3), ix = ldexpf(1.f, 3 - ex);
    float dy = ldexpf(1.f, ey - 3), iy = ldexpf(1.f, 3 - ey);
    float dz = ldexpf(1.f, ez - 3), iz = ldexpf(1.f, 3 - ez);
    float dw = ldexpf(1.f, ew - 3), iw = ldexpf(1.f, 3 - ew);

    // ---- pass B: re-read (L3-hit), quantize, nontemporal store ----
#pragma unroll
    for (int i = 0; i < CHUNK; ++i) {
        float4 v = p[i * HW4];
        vfloat4 r;
        r.x = truncf(v.x * ix) * dx;
        r.y = truncf(v.y * iy) * dy;
        r.z = truncf(v.z * iz) * dz;
        r.w = truncf(v.w * iw) * dw;
        __builtin_nontemporal_store(r, (vfloat4*)&q[i * HW4]);
    }
}

extern "C" void kernel_launch(void* const* d_in, const int* in_sizes, int n_in,
                              void* d_out, int out_size, void* d_ws, size_t ws_size,
                              hipStream_t stream) {
    const float* in = (const float*)d_in[0];
    float* out      = (float*)d_out;
    int N      = in_sizes[0] / (C * HW);        // 64
    int total4 = N * HW4;                       // 50176 float4 sites
    int waves  = (total4 + 3) / 4;              // 4 sites per wave
    int blocks = (waves + 3) / 4;               // 4 waves per 256-thread block
    bfp_kernel<<<blocks, 256, 0, stream>>>((const float4*)in, (float4*)out, total4);
}